// Round 14
// baseline (54.625 us; speedup 1.0000x reference)
//
#include <hip/hip_runtime.h>
#include <hip/hip_bf16.h>

// SelfAttention: B=4, S=4096, Din=768, Dout=64.
// R14: unbundle R13's failure.
//  attn: byte-exact revert to validated R12 (LDS P round-trip + lgkm fence).
//  proj: keep R13 mixed-depth staging (x HBM-latency staged 2 iters ahead in
//        4 bufs, wb L2 1 ahead in 3 bufs, vmcnt(7)/iter) — FIFO audited for
//        all 12 iters incl. wrap.
//  If this passes: proj exonerated; R13's in-register-P exchange (cvt_pk asm)
//  was the bug — retry later with compiler-generated packing as the ONLY change.

typedef __attribute__((ext_vector_type(8))) __bf16 bf16x8;
typedef __attribute__((ext_vector_type(4))) __bf16 bf16x4;
typedef __attribute__((ext_vector_type(4))) float  f32x4;

constexpr int BATCH = 4;
constexpr int SEQ   = 4096;
constexpr int DIN   = 768;
constexpr int NTOT  = 192;
constexpr int MROWS = BATCH * SEQ;  // 16384
constexpr int KVT   = 128;          // kv tile (128 rows x 128B K, 64 x 256B V)

__device__ __forceinline__ f32x4 mfma16(bf16x8 a, bf16x8 b, f32x4 c) {
    return __builtin_amdgcn_mfma_f32_16x16x32_bf16(a, b, c, 0, 0, 0);
}

__device__ __forceinline__ void gload_lds16(const void* g, void* l) {
    __builtin_amdgcn_global_load_lds(
        (const __attribute__((address_space(1))) void*)g,
        (__attribute__((address_space(3))) void*)l, 16, 0, 0);
}

// ---------------- k0: pack Wq|Wk|Wv -> bf16 [192][768]; Wq pre-scaled by
// 0.125*log2(e) so attention scores come out in exp2 domain.
__global__ __launch_bounds__(256) void convert_w(
        const float* __restrict__ Wq, const float* __restrict__ Wk,
        const float* __restrict__ Wv, __bf16* __restrict__ wb) {
    int i = blockIdx.x * 256 + threadIdx.x;
    if (i >= NTOT * DIN) return;
    int n = i / DIN;
    const float* src = (n < 64) ? Wq : (n < 128) ? Wk : Wv;
    float scale = (n < 64) ? 0.125f * 1.44269504f : 1.0f;
    wb[i] = (__bf16)(src[(n & 63) * DIN + (i % DIN)] * scale);
}

// ---------------- k1: q,k,v = x @ W^T  (M=16384, N=192, K=768)
// grid = 256 blocks of 64 rows; 8 waves = 4 row-strips x 2 n-halves.
// wb: 3 bufs, staged 1 ahead (L2-resident). x: 4 bufs, staged 2 ahead
// (HBM latency). Per iter: 3 wb ops + 2 x ops issued; vmcnt(7) leaves
// {x(t+1), wb(t+1), x(t+2)} = 7 in flight.
__global__ __launch_bounds__(512, 2) void qkv_proj(
        const float* __restrict__ x, const __bf16* __restrict__ wb,
        __bf16* __restrict__ q, __bf16* __restrict__ k, __bf16* __restrict__ vT) {
    const int tid  = threadIdx.x;
    const int wave = tid >> 6, lane = tid & 63;
    const int strip = wave & 3, nh = wave >> 2;
    const int lr = lane & 15;
    const int g  = lane >> 4;
    const int rx = (lr & 7) << 4;

    __shared__ __align__(16) char wbuf[3][NTOT * 128];   // 72 KiB
    __shared__ __align__(16) char xbuf[4][64 * 256];     // 64 KiB

    const int  srow = lane >> 3;                          // wb: 8 rows/instr
    const int  ssw  = ((lane & 7) << 4) ^ ((srow & 7) << 4);
    const int  xs4  = lane >> 4;                          // x: 4 rows/instr
    const char* wbb = (const char*)wb;
    const char* xbb = (const char*)x;
    const int  xrow0 = blockIdx.x * 64;

    auto stage_w = [&](int buf, int kt) {
#pragma unroll
        for (int s = 0; s < 3; ++s) {                     // 3 ops/wave
            const int rbase = wave * 24 + s * 8;
            gload_lds16(wbb + (size_t)(rbase + srow) * (DIN * 2) + kt * 128 + ssw,
                        &wbuf[buf][rbase * 128]);
        }
    };
    auto stage_x = [&](int buf, int kt) {
#pragma unroll
        for (int s = 0; s < 2; ++s) {                     // 2 ops/wave
            const int xr = wave * 8 + s * 4;
            const int sswx = ((lane & 15) ^ ((xr & 15) + xs4)) << 4;
            gload_lds16(xbb + (size_t)(xrow0 + xr + xs4) * (DIN * 4) +
                            kt * 256 + sswx,
                        &xbuf[buf][xr * 256]);
        }
    };

    f32x4 acc[6];
#pragma unroll
    for (int t = 0; t < 6; ++t) acc[t] = f32x4{0.f, 0.f, 0.f, 0.f};

    stage_w(0, 0);
    stage_x(0, 0);
    stage_x(1, 1);
    asm volatile("s_waitcnt vmcnt(2) lgkmcnt(0)" ::: "memory");  // x(1) in flight
    __builtin_amdgcn_s_barrier();

    constexpr int NT = DIN / 64;   // 12
    for (int kt = 0; kt < NT; ++kt) {
        stage_w((kt + 1) % 3, (kt + 1) % NT);             // wrap: count const
        stage_x((kt + 2) & 3, (kt + 2) % NT);
        asm volatile("s_waitcnt vmcnt(7) lgkmcnt(0)" ::: "memory");
        __builtin_amdgcn_s_barrier();

        const char* wbc = wbuf[kt % 3];
        const char* xbc = xbuf[kt & 3];
#pragma unroll
        for (int ks = 0; ks < 2; ++ks) {
            const char* xrp = xbc + (strip * 16 + lr) * 256;
            f32x4 xa = *(const f32x4*)(xrp + ((ks * 128 + g * 32)      ^ (lr << 4)));
            f32x4 xb = *(const f32x4*)(xrp + ((ks * 128 + g * 32 + 16) ^ (lr << 4)));
            bf16x8 af;
            af[0] = (__bf16)xa[0]; af[1] = (__bf16)xa[1]; af[2] = (__bf16)xa[2]; af[3] = (__bf16)xa[3];
            af[4] = (__bf16)xb[0]; af[5] = (__bf16)xb[1]; af[6] = (__bf16)xb[2]; af[7] = (__bf16)xb[3];
#pragma unroll
            for (int t = 0; t < 6; ++t) {
                const int nr = (nh * 6 + t) * 16 + lr;
                bf16x8 bf = *(const bf16x8*)(wbc + nr * 128 +
                                             ((ks * 64 + g * 16) ^ rx));
                acc[t] = mfma16(af, bf, acc[t]);
            }
        }
    }

    const int orow = blockIdx.x * 64 + strip * 16 + g * 4;
#pragma unroll
    for (int t = 0; t < 6; ++t) {
        int n = (nh * 6 + t) * 16 + lr;
#pragma unroll
        for (int r = 0; r < 4; ++r) {
            int m = orow + r;
            __bf16 hv = (__bf16)acc[t][r];
            if (n < 64) {
                q[(size_t)m * 64 + n] = hv;
            } else if (n < 128) {
                k[(size_t)m * 64 + (n - 64)] = hv;
            } else {
                int b = m >> 12, s = m & (SEQ - 1);
                vT[(size_t)b * 64 * SEQ + (size_t)(n - 128) * SEQ + s] = hv;
            }
        }
    }
}

// ---------------- k2: flash attention, LDS-staged K/V, 16 waves.  [= R12]
// grid = (SEQ/64, BATCH) = 256 blocks, 1024 threads
// (4 q-strips x 4 kv-parities). Parity p computes kv rows [p*32, p*32+32)
// of each staged 128-row tile. Triple-buffered, counted vmcnt(2).
__global__ __launch_bounds__(1024, 4) void attn(
        const __bf16* __restrict__ q, const __bf16* __restrict__ k,
        const __bf16* __restrict__ vT, float* __restrict__ out) {
    const int tid  = threadIdx.x;
    const int wave = tid >> 6, lane = tid & 63;
    const int strip = wave & 3, par = wave >> 2;
    const int b  = blockIdx.y;
    const int q0 = blockIdx.x * 64 + strip * 16;
    const int lr = lane & 15;
    const int g  = lane >> 4;
    const int lk = g * 8;
    const int rx = (lr & 7) << 4;

    const __bf16* qp = q  + (size_t)b * SEQ * 64;
    const __bf16* kp = k  + (size_t)b * SEQ * 64;
    const __bf16* vp = vT + (size_t)b * 64 * SEQ;

    __shared__ __align__(16) char kbuf[3][KVT * 128];   // 48 KiB (128r x 128B)
    __shared__ __align__(16) char vbuf[3][64 * 256];    // 48 KiB (64r x 256B)
    __shared__ __align__(16) char pbuf[16][2048];       // 32 KiB
    char* pw = &pbuf[wave][0];

    const int  srow8 = lane >> 3;                        // K: 8 rows/instr
    const int  sswK  = ((lane & 7) << 4) ^ ((srow8 & 7) << 4);
    const int  vrow  = wave * 4 + (lane >> 4);           // V: 4 rows/instr
    const int  sswV  = ((lane & 15) ^ (vrow & 7)) << 4;

    auto stage = [&](int buf, int kv0) {   // exactly 2 VMEM ops per wave
        gload_lds16((const char*)kp + (size_t)(kv0 + wave * 8 + srow8) * 128 + sswK,
                    &kbuf[buf][wave * 8 * 128]);
        gload_lds16((const char*)vp + (size_t)vrow * (SEQ * 2) +
                        (size_t)kv0 * 2 + sswV,
                    &vbuf[buf][wave * 4 * 256]);
    };

    bf16x8 qf0 = *(const bf16x8*)(qp + (size_t)(q0 + lr) * 64 + lk);
    bf16x8 qf1 = *(const bf16x8*)(qp + (size_t)(q0 + lr) * 64 + 32 + lk);

    f32x4 acc_o[4];
#pragma unroll
    for (int t = 0; t < 4; ++t) acc_o[t] = f32x4{0.f, 0.f, 0.f, 0.f};
    float l_run = 0.f;

    stage(0, 0);
    asm volatile("s_waitcnt vmcnt(0) lgkmcnt(0)" ::: "memory");
    __builtin_amdgcn_s_barrier();

    constexpr int NT = SEQ / KVT;   // 32
    int cur = 0, nxt = 1;
    for (int it = 0; it < NT; ++it) {
        stage(nxt, ((it + 1) & (NT - 1)) * KVT);          // wrap keeps count const
        asm volatile("s_waitcnt vmcnt(2) lgkmcnt(0)" ::: "memory");
        __builtin_amdgcn_s_barrier();

        // ---- S^T = K Q^T on parity's 32 kv rows (exp2 domain)
        f32x4 s4[2];
#pragma unroll
        for (int j = 0; j < 2; ++j) {
            const char* kr = &kbuf[cur][(par * 32 + j * 16 + lr) * 128];
            bf16x8 kf0 = *(const bf16x8*)(kr + ((g * 16) ^ rx));
            bf16x8 kf1 = *(const bf16x8*)(kr + ((64 + g * 16) ^ rx));
            f32x4 a = f32x4{0.f, 0.f, 0.f, 0.f};
            a = mfma16(kf0, qf0, a);
            a = mfma16(kf1, qf1, a);
            s4[j] = a;
        }

        // ---- max-free softmax; pack P (16q x 32kv, swizzled rows of 128B)
#pragma unroll
        for (int j = 0; j < 2; ++j) {
            bf16x4 pbv;
#pragma unroll
            for (int r = 0; r < 4; ++r) {
                float p = __builtin_amdgcn_exp2f(s4[j][r]);
                l_run += p;
                pbv[r] = (__bf16)p;
            }
            *(bf16x4*)(pw + lr * 128 + ((j * 32 + g * 8) ^ rx)) = pbv;
        }
        asm volatile("s_waitcnt lgkmcnt(0)" ::: "memory");

        // ---- O^T += V^T P on parity's kv slice (one 32-wide K-step)
        bf16x8 pf = *(const bf16x8*)(pw + lr * 128 + ((g * 16) ^ rx));
#pragma unroll
        for (int t = 0; t < 4; ++t) {
            const char* vr = &vbuf[cur][(t * 16 + lr) * 256];
            bf16x8 vf = *(const bf16x8*)(vr + ((par * 64 + g * 16) ^ rx));
            acc_o[t] = mfma16(vf, pf, acc_o[t]);
        }

        cur = nxt; nxt = (nxt == 2) ? 0 : nxt + 1;
    }

    // ---- 4-parity merge (plain sums: max-free). kbuf/vbuf dead -> reuse.
    l_run += __shfl_xor(l_run, 16);
    l_run += __shfl_xor(l_run, 32);
    __syncthreads();   // full drain (incl. wrap prefetch) before LDS reuse

    float* mo = (float*)(&kbuf[0][0]);   // [3][4][16][64] f32 = 48 KiB
    float* ml = (float*)(&vbuf[0][0]);   // [3][4][16] f32
    if (par > 0) {
        const int pi = par - 1;
        float* dst = mo + (size_t)((pi * 4 + strip) * 16 + lr) * 64;
#pragma unroll
        for (int t = 0; t < 4; ++t)
            *(f32x4*)(dst + t * 16 + g * 4) = acc_o[t];
        if (lane < 16) ml[(pi * 4 + strip) * 16 + lr] = l_run;
    }
    __syncthreads();
    if (par == 0) {
        float L = l_run;
#pragma unroll
        for (int pi = 0; pi < 3; ++pi) L += ml[(pi * 4 + strip) * 16 + lr];
        float inv = 1.f / L;
        float* ob = out + ((size_t)b * SEQ + q0 + lr) * 64;
#pragma unroll
        for (int t = 0; t < 4; ++t) {
            f32x4 o4 = acc_o[t];
#pragma unroll
            for (int pi = 0; pi < 3; ++pi)
                o4 += *(const f32x4*)(mo + (size_t)((pi * 4 + strip) * 16 + lr) * 64 +
                                      t * 16 + g * 4);
#pragma unroll
            for (int r = 0; r < 4; ++r) o4[r] *= inv;
            *(f32x4*)(ob + t * 16 + g * 4) = o4;
        }
    }
}

extern "C" void kernel_launch(void* const* d_in, const int* in_sizes, int n_in,
                              void* d_out, int out_size, void* d_ws, size_t ws_size,
                              hipStream_t stream) {
    const float* x  = (const float*)d_in[0];
    const float* Wq = (const float*)d_in[1];
    const float* Wk = (const float*)d_in[2];
    const float* Wv = (const float*)d_in[3];
    float* out = (float*)d_out;

    char* ws = (char*)d_ws;
    __bf16* wb = (__bf16*)(ws);
    __bf16* qb = (__bf16*)(ws + 294912);
    __bf16* kb = (__bf16*)(ws + 294912 + 2097152);
    __bf16* vT = (__bf16*)(ws + 294912 + 2u * 2097152);

    convert_w<<<dim3((NTOT * DIN + 255) / 256), dim3(256), 0, stream>>>(Wq, Wk, Wv, wb);
    qkv_proj<<<dim3(MROWS / 64), dim3(512), 0, stream>>>(x, wb, qb, kb, vT);
    attn<<<dim3(SEQ / 64, BATCH), dim3(1024), 0, stream>>>(qb, kb, vT, out);
}